// Round 1
// baseline (655.507 us; speedup 1.0000x reference)
//
#include <hip/hip_runtime.h>
#include <hip/hip_bf16.h>

#define B_ 256
#define N_ 256
#define M_ 256
#define D_ 1024
#define RAD 128
#define BIGF 1e30f

typedef short bf16x8 __attribute__((ext_vector_type(8)));
typedef float f32x4 __attribute__((ext_vector_type(4)));

__device__ __forceinline__ short f2bf(float f) {
    __hip_bfloat16 h = __float2bfloat16(f);
    return __builtin_bit_cast(short, h);
}

__device__ __forceinline__ void cvt4(const float4 v, short* s, float& n) {
    n += v.x * v.x + v.y * v.y + v.z * v.z + v.w * v.w;
    s[0] = f2bf(v.x); s[1] = f2bf(v.y); s[2] = f2bf(v.z); s[3] = f2bf(v.w);
}

// Phase 1: per-batch bf16 MFMA GEMM sim = X.Y^T with fused row-norm
// computation; epilogue writes dist = 1 - clamp(sim*rnx*rny, -1, 1).
// Grid: 256 batches x 4 tiles of 128x128. Block: 256 threads (4 waves),
// each wave owns a 64x64 subtile as 4x4 fragments of 16x16x32 bf16 MFMA.
__global__ __launch_bounds__(256) void gemm_dist_kernel(
        const float* __restrict__ X, const float* __restrict__ Y,
        float* __restrict__ dist) {
    const int bid = blockIdx.x;
    const int b  = bid >> 2;
    const int ti = (bid >> 1) & 1;
    const int tj = bid & 1;

    __shared__ short As[128][32];   // [row][k] bf16, 64B row stride
    __shared__ short Bs[128][32];
    __shared__ float redA[256];
    __shared__ float redB[256];
    __shared__ float rnx[128];
    __shared__ float rny[128];

    const int t    = threadIdx.x;
    const int row  = t >> 1;          // staged row 0..127 (A and B)
    const int kh   = (t & 1) << 4;    // k half: 0 or 16
    const int wave = t >> 6;
    const int lane = t & 63;
    const int wi   = (wave >> 1) << 6;
    const int wj   = (wave & 1) << 6;
    const int fq   = lane >> 4;       // quad 0..3
    const int fr   = lane & 15;

    const float* ax = X + (((size_t)b * N_ + ti * 128 + row) * D_) + kh;
    const float* by = Y + (((size_t)b * M_ + tj * 128 + row) * D_) + kh;

    f32x4 acc[4][4];
    const f32x4 zero = {0.f, 0.f, 0.f, 0.f};
#pragma unroll
    for (int r = 0; r < 4; ++r)
#pragma unroll
        for (int c = 0; c < 4; ++c) acc[r][c] = zero;

    float nA = 0.f, nB = 0.f;

    for (int kt = 0; kt < D_ / 32; ++kt) {
        // Global fp32 loads: each thread reads a contiguous 64B span of its
        // row (A and B), i.e. one full cache line each.
        const float4 va0 = *(const float4*)(ax + 0);
        const float4 va1 = *(const float4*)(ax + 4);
        const float4 va2 = *(const float4*)(ax + 8);
        const float4 va3 = *(const float4*)(ax + 12);
        const float4 vb0 = *(const float4*)(by + 0);
        const float4 vb1 = *(const float4*)(by + 4);
        const float4 vb2 = *(const float4*)(by + 8);
        const float4 vb3 = *(const float4*)(by + 12);
        ax += 32; by += 32;

        short sa[16], sb[16];
        cvt4(va0, sa + 0,  nA); cvt4(va1, sa + 4,  nA);
        cvt4(va2, sa + 8,  nA); cvt4(va3, sa + 12, nA);
        cvt4(vb0, sb + 0,  nB); cvt4(vb1, sb + 4,  nB);
        cvt4(vb2, sb + 8,  nB); cvt4(vb3, sb + 12, nB);

        __syncthreads();   // previous iteration's MFMA LDS reads complete
        *(bf16x8*)&As[row][kh]     = *(bf16x8*)&sa[0];
        *(bf16x8*)&As[row][kh + 8] = *(bf16x8*)&sa[8];
        *(bf16x8*)&Bs[row][kh]     = *(bf16x8*)&sb[0];
        *(bf16x8*)&Bs[row][kh + 8] = *(bf16x8*)&sb[8];
        __syncthreads();

        bf16x8 af[4], bf[4];
#pragma unroll
        for (int r = 0; r < 4; ++r)
            af[r] = *(const bf16x8*)&As[wi + r * 16 + fr][fq * 8];
#pragma unroll
        for (int c = 0; c < 4; ++c)
            bf[c] = *(const bf16x8*)&Bs[wj + c * 16 + fr][fq * 8];
#pragma unroll
        for (int r = 0; r < 4; ++r)
#pragma unroll
            for (int c = 0; c < 4; ++c)
                acc[r][c] = __builtin_amdgcn_mfma_f32_16x16x32_bf16(
                    af[r], bf[c], acc[r][c], 0, 0, 0);
    }

    // Row norms: thread t and t^1 jointly covered row t>>1 over all K.
    redA[t] = nA;
    redB[t] = nB;
    __syncthreads();
    if (t < 128) {
        float sA = redA[2 * t] + redA[2 * t + 1];
        float sB = redB[2 * t] + redB[2 * t + 1];
        rnx[t] = 1.0f / fmaxf(sqrtf(sA), 1e-12f);
        rny[t] = 1.0f / fmaxf(sqrtf(sB), 1e-12f);
    }
    __syncthreads();

    // Epilogue: C/D layout col=lane&15, row=quad*4+reg (m89-verified).
    float* Dp = dist + (((size_t)b * N_ + ti * 128) * M_) + tj * 128;
#pragma unroll
    for (int r = 0; r < 4; ++r) {
#pragma unroll
        for (int c = 0; c < 4; ++c) {
            const int col = wj + c * 16 + fr;
            const float rc = rny[col];
#pragma unroll
            for (int g = 0; g < 4; ++g) {
                const int rw = wi + r * 16 + fq * 4 + g;
                float v = acc[r][c][g] * rnx[rw] * rc;
                v = fminf(1.0f, fmaxf(-1.0f, v));
                Dp[(size_t)rw * M_ + col] = 1.0f - v;
            }
        }
    }
}

// Phase 2: banded DTW, one wave per batch. Lane l owns columns 4l..4l+3.
// Row recurrence a[j] = min(bt[j], a[j-1]+st[j]) solved as a min-plus scan:
// within-lane fold of (s,t) pairs + 6-step shfl_up wave scan. No barriers.
__global__ __launch_bounds__(64) void dtw_kernel(
        const float* __restrict__ dist, float* __restrict__ out) {
    const int b = blockIdx.x;
    const int lane = threadIdx.x;
    const float* Db = dist + (size_t)b * N_ * M_;
    const int j0 = lane << 2;

    // ---- row 0: masked cumulative sum ----
    float4 d = *(const float4*)(Db + j0);
    float s0 = d.x, s1 = s0 + d.y, s2 = s1 + d.z, s3 = s2 + d.w;
    float tot = s3;
#pragma unroll
    for (int off = 1; off < 64; off <<= 1) {
        float o = __shfl_up(tot, off);
        if (lane >= off) tot += o;
    }
    float excl = __shfl_up(tot, 1);
    if (lane == 0) excl = 0.f;
    float prev[4];
    prev[0] = (j0 + 0 <= RAD) ? excl + s0 : BIGF;
    prev[1] = (j0 + 1 <= RAD) ? excl + s1 : BIGF;
    prev[2] = (j0 + 2 <= RAD) ? excl + s2 : BIGF;
    prev[3] = (j0 + 3 <= RAD) ? excl + s3 : BIGF;

    float4 dn = *(const float4*)(Db + M_ + j0);  // prefetch row 1

    for (int i = 1; i < N_; ++i) {
        d = dn;
        if (i + 1 < N_) dn = *(const float4*)(Db + (size_t)(i + 1) * M_ + j0);

        const float pm1 = __shfl_up(prev[3], 1);        // prev[j-1] at slot 0
        const float p00 = __shfl(prev[0], 0);
        const float d00 = __shfl(d.x, 0);
        const float a0 = (i <= RAD) ? p00 + d00 : BIGF;

        const float de[4] = {d.x, d.y, d.z, d.w};
        const float ps[4] = {pm1, prev[0], prev[1], prev[2]};

        // within-lane inclusive fold of (st, bt) pairs; element j==0 is the
        // monoid identity (0, +BIG)
        float S = 0.f, T = BIGF;
        float Se[4], Te[4];
#pragma unroll
        for (int e = 0; e < 4; ++e) {
            const int j = j0 + e;
            float st, bt;
            if (j == 0) {
                st = 0.f; bt = BIGF;
            } else {
                const bool in = (j >= i - RAD) && (j <= i + RAD);
                const float c = fminf(prev[e], ps[e]);
                bt = in ? c + de[e] : BIGF;
                st = in ? de[e] : BIGF;
            }
            T = fminf(bt, T + st);   // comb(p, x)
            S = S + st;
            Se[e] = S; Te[e] = T;
        }

        // wave inclusive scan of lane totals with comb(left, self)
        float iS = S, iT = T;
#pragma unroll
        for (int off = 1; off < 64; off <<= 1) {
            float oS = __shfl_up(iS, off);
            float oT = __shfl_up(iT, off);
            if (lane >= off) {
                iT = fminf(iT, oT + iS);
                iS = oS + iS;
            }
        }
        float eS = __shfl_up(iS, 1);
        float eT = __shfl_up(iT, 1);
        if (lane == 0) { eS = 0.f; eT = BIGF; }

#pragma unroll
        for (int e = 0; e < 4; ++e) {
            const float fS = eS + Se[e];
            const float fT = fminf(Te[e], eT + Se[e]);
            prev[e] = fminf(fT, a0 + fS);
        }
        if (lane == 0) prev[0] = a0;
    }

    if (lane == 63) out[b] = prev[3];
}

extern "C" void kernel_launch(void* const* d_in, const int* in_sizes, int n_in,
                              void* d_out, int out_size, void* d_ws, size_t ws_size,
                              hipStream_t stream) {
    const float* seq1 = (const float*)d_in[0];
    const float* seq2 = (const float*)d_in[1];
    float* out = (float*)d_out;
    float* dist = (float*)d_ws;   // 256*256*256*4 = 64 MiB scratch

    hipLaunchKernelGGL(gemm_dist_kernel, dim3(B_ * 4), dim3(256), 0, stream,
                       seq1, seq2, dist);
    hipLaunchKernelGGL(dtw_kernel, dim3(B_), dim3(64), 0, stream, dist, out);
}